// Round 1
// baseline (780.653 us; speedup 1.0000x reference)
//
#include <hip/hip_runtime.h>
#include <stdint.h>

typedef unsigned int u32;
typedef unsigned long long u64;

#define B_IMG 16
#define NBINS 4096
#define CAP   4096
#define SORT_N 4096
#define TOPK  1000
#define NWORDS 16   /* ceil(1000/64) */

#define HW0 16384
#define HW1 4096
#define HW2 1024
#define L0  147456   /* 9*HW0 per image */
#define L1  36864
#define L2  9216
#define NANCH 193536
#define O1  147456
#define O2  184320

__device__ __forceinline__ float score_of(float x) {
    return 1.0f / (1.0f + expf(-x));
}

__device__ __forceinline__ float load_logit(int b, int n,
        const float* __restrict__ c0, const float* __restrict__ c1,
        const float* __restrict__ c2) {
    if (n < O1)      return c0[b * L0 + n];
    else if (n < O2) return c1[b * L1 + (n - O1)];
    else             return c2[b * L2 + (n - O2)];
}

// ---------------- kernel 1: per-image score histogram ----------------
__global__ void k_hist(const float* __restrict__ c0, const float* __restrict__ c1,
                       const float* __restrict__ c2, u32* __restrict__ hist) {
    __shared__ u32 lh[NBINS];
    for (int i = threadIdx.x; i < NBINS; i += blockDim.x) lh[i] = 0;
    __syncthreads();
    const int b  = blockIdx.y;
    const int n0 = blockIdx.x * 16384;
    for (int t = threadIdx.x; t < 16384; t += blockDim.x) {
        int n = n0 + t;
        if (n < NANCH) {
            float s = score_of(load_logit(b, n, c0, c1, c2));
            int bin = (int)(s * (float)NBINS);
            bin = min(max(bin, 0), NBINS - 1);
            atomicAdd(&lh[bin], 1u);
        }
    }
    __syncthreads();
    for (int i = threadIdx.x; i < NBINS; i += blockDim.x) {
        u32 v = lh[i];
        if (v) atomicAdd(&hist[b * NBINS + i], v);
    }
}

// ---------------- kernel 2: find per-image threshold bin ----------------
__global__ void k_thresh(const u32* __restrict__ hist, u32* __restrict__ tbin) {
    int b = threadIdx.x;
    if (b >= B_IMG) return;
    u32 cum = 0;
    int T = 0;
    for (int bin = NBINS - 1; bin >= 0; --bin) {
        cum += hist[b * NBINS + bin];
        if (cum >= TOPK) { T = bin; break; }
    }
    tbin[b] = (u32)T;
}

// ---------------- kernel 3: collect candidates ----------------
__global__ void k_collect(const float* __restrict__ c0, const float* __restrict__ c1,
                          const float* __restrict__ c2, const u32* __restrict__ tbin,
                          u32* __restrict__ cnt, uint2* __restrict__ cand) {
    const int b  = blockIdx.y;
    const int T  = (int)tbin[b];
    const int n0 = blockIdx.x * 16384;
    for (int t = threadIdx.x; t < 16384; t += blockDim.x) {
        int n = n0 + t;
        if (n < NANCH) {
            float s = score_of(load_logit(b, n, c0, c1, c2));
            int bin = (int)(s * (float)NBINS);
            bin = min(max(bin, 0), NBINS - 1);
            if (bin >= T) {
                u32 pos = atomicAdd(&cnt[b], 1u);
                if (pos < CAP)
                    cand[b * CAP + pos] = make_uint2(__float_as_uint(s), (u32)n);
            }
        }
    }
}

// ---------------- box decode for one anchor ----------------
__device__ __forceinline__ float4 decode_one(u32 n, int b,
        const float* __restrict__ bx0, const float* __restrict__ bx1,
        const float* __restrict__ bx2) {
    int a, p, X, Y, stride, HW;
    float base;
    const float* bptr;
    if (n < O1) {
        a = n >> 14; p = n & (HW0 - 1); X = p & 127; Y = p >> 7;
        stride = 8; base = 32.0f; HW = HW0;
        bptr = bx0 + ((b * 9 + a) * 4) * HW0 + p;
    } else if (n < O2) {
        u32 wi = n - O1;
        a = wi >> 12; p = wi & (HW1 - 1); X = p & 63; Y = p >> 6;
        stride = 16; base = 64.0f; HW = HW1;
        bptr = bx1 + ((b * 9 + a) * 4) * HW1 + p;
    } else {
        u32 wi = n - O2;
        a = wi >> 10; p = wi & (HW2 - 1); X = p & 31; Y = p >> 5;
        stride = 32; base = 128.0f; HW = HW2;
        bptr = bx2 + ((b * 9 + a) * 4) * HW2 + p;
    }
    float tx = bptr[0], ty = bptr[HW], tw = bptr[2 * HW], th = bptr[3 * HW];
    int sci = a / 3, ri = a % 3;
    const float SCALE3[3] = {1.0f, 1.2599210498948732f, 1.5874010519681994f};
    const float SQRTR[3]  = {0.7071067811865476f, 1.0f, 1.4142135623730951f};
    float size = base * SCALE3[sci];
    float aw = size * SQRTR[ri];
    float ah = size / SQRTR[ri];
    float cx = ((float)X + 0.5f) * (float)stride;
    float cy = ((float)Y + 0.5f) * (float)stride;
    float gx = tx * aw + cx;
    float gy = ty * ah + cy;
    float gw = aw * expf(tw);
    float gh = ah * expf(th);
    return make_float4(gx - 0.5f * gw, gy - 0.5f * gh, gx + 0.5f * gw, gy + 0.5f * gh);
}

// ---------------- kernel 4: per-image bitonic sort + top-1000 decode ----------------
__global__ __launch_bounds__(1024) void k_sort(const u32* __restrict__ cnt,
        const uint2* __restrict__ cand,
        const float* __restrict__ bx0, const float* __restrict__ bx1,
        const float* __restrict__ bx2,
        float4* __restrict__ tbox, float* __restrict__ tsc) {
    __shared__ u64 keys[SORT_N];
    const int b = blockIdx.x;
    int m = (int)min(cnt[b], (u32)CAP);
    for (int i = threadIdx.x; i < SORT_N; i += blockDim.x) {
        u64 k = 0;
        if (i < m) {
            uint2 c = cand[b * CAP + i];
            k = ((u64)c.x << 32) | (u64)((u32)(~c.y));
        }
        keys[i] = k;
    }
    __syncthreads();
    for (int k = 2; k <= SORT_N; k <<= 1) {
        for (int j = k >> 1; j > 0; j >>= 1) {
            for (int i = threadIdx.x; i < SORT_N; i += (int)blockDim.x) {
                int ixj = i ^ j;
                if (ixj > i) {
                    u64 a = keys[i], bb = keys[ixj];
                    bool up = ((i & k) == 0);
                    // descending sort
                    if (up ? (a < bb) : (a > bb)) { keys[i] = bb; keys[ixj] = a; }
                }
            }
            __syncthreads();
        }
    }
    if (threadIdx.x < TOPK) {
        int r = threadIdx.x;
        u64 kk = keys[r];
        float s = __uint_as_float((u32)(kk >> 32));
        u32 n = ~((u32)kk);
        float4 box = decode_one(n, b, bx0, bx1, bx2);
        tsc[b * TOPK + r] = s;
        tbox[b * TOPK + r] = box;
    }
}

// ---------------- kernel 5: suppression bitmask (iou > 0.5 && j > i) ----------------
__global__ void k_mask(const float4* __restrict__ tbox, u64* __restrict__ mask) {
    __shared__ float4 bl[TOPK];
    const int b = blockIdx.y;
    for (int i = threadIdx.x; i < TOPK; i += blockDim.x)
        bl[i] = tbox[b * TOPK + i];
    __syncthreads();
    int wv = threadIdx.x >> 6, lane = threadIdx.x & 63;
    int rstart = blockIdx.x * 250;
    for (int r = wv; r < 250; r += 4) {
        int i = rstart + r;
        float4 bi = bl[i];
        float areai = (bi.z - bi.x) * (bi.w - bi.y);
        u64 myword = 0;
        for (int c = 0; c < NWORDS; ++c) {
            int j = c * 64 + lane;
            bool pred = false;
            if (j < TOPK && j > i) {
                float4 bj = bl[j];
                float xx1 = fmaxf(bi.x, bj.x), yy1 = fmaxf(bi.y, bj.y);
                float xx2 = fminf(bi.z, bj.z), yy2 = fminf(bi.w, bj.w);
                float iw = fmaxf(xx2 - xx1, 0.0f), ih = fmaxf(yy2 - yy1, 0.0f);
                float inter = iw * ih;
                float areaj = (bj.z - bj.x) * (bj.w - bj.y);
                float iou = inter / (areai + areaj - inter + 1e-8f);
                pred = iou > 0.5f;
            }
            u64 bal = __ballot(pred);
            if (lane == c) myword = bal;
        }
        if (lane < NWORDS)
            mask[((u64)b * TOPK + i) * NWORDS + lane] = myword;
    }
}

// ---------------- kernel 6: serial greedy NMS + output ----------------
__global__ void k_nms_out(const float4* __restrict__ tbox, const float* __restrict__ tsc,
                          const u64* __restrict__ mask, float* __restrict__ out) {
    const int b = blockIdx.x;
    __shared__ float sc[TOPK];
    __shared__ u32 kp[TOPK];
    int lane = threadIdx.x;  // 64 threads = 1 wave
    for (int i = lane; i < TOPK; i += 64) sc[i] = tsc[b * TOPK + i];
    __syncthreads();
    u64 sup = 0;
    const u64* mrow = mask + (u64)b * TOPK * NWORDS;
    for (int i = 0; i < TOPK; ++i) {
        u64 wv = __shfl(sup, i >> 6);
        bool suppressed = (wv >> (i & 63)) & 1ull;
        bool keep = (!suppressed) && (sc[i] > 0.05f);
        if (lane == 0) kp[i] = keep ? 1u : 0u;
        if (keep && lane < NWORDS) sup |= mrow[(u64)i * NWORDS + lane];
    }
    __syncthreads();
    for (int j = lane; j < TOPK; j += 64) {
        float kf = kp[j] ? 1.0f : 0.0f;
        float4 bx = tbox[b * TOPK + j];
        float s = sc[j];
        float* o = out + ((u64)b * TOPK + j) * 5;
        o[0] = bx.x * kf;
        o[1] = bx.y * kf;
        o[2] = bx.z * kf;
        o[3] = bx.w * kf;
        o[4] = s * kf;
    }
}

extern "C" void kernel_launch(void* const* d_in, const int* in_sizes, int n_in,
                              void* d_out, int out_size, void* d_ws, size_t ws_size,
                              hipStream_t stream) {
    const float* c0 = (const float*)d_in[0];
    const float* c1 = (const float*)d_in[1];
    const float* c2 = (const float*)d_in[2];
    const float* b0 = (const float*)d_in[3];
    const float* b1 = (const float*)d_in[4];
    const float* b2 = (const float*)d_in[5];

    char* ws = (char*)d_ws;
    size_t off = 0;
    u32*   hist = (u32*)(ws + off);  off += (size_t)B_IMG * NBINS * 4;   // 256 KiB
    u32*   tbin = (u32*)(ws + off);  off += 256;
    u32*   cnt  = (u32*)(ws + off);  off += 256;
    uint2* cand = (uint2*)(ws + off); off += (size_t)B_IMG * CAP * 8;    // 512 KiB
    float4* tbox = (float4*)(ws + off); off += (size_t)B_IMG * TOPK * 16;
    float*  tsc  = (float*)(ws + off);  off += (size_t)B_IMG * TOPK * 4;
    u64*    mask = (u64*)(ws + off);    off += (size_t)B_IMG * TOPK * NWORDS * 8; // 2 MiB
    // total ~3.1 MiB of d_ws used

    // zero hist + tbin + cnt every call (harness does not re-poison between replays)
    hipMemsetAsync(d_ws, 0, (size_t)B_IMG * NBINS * 4 + 512, stream);

    dim3 g1(12, B_IMG);
    k_hist<<<g1, 256, 0, stream>>>(c0, c1, c2, hist);
    k_thresh<<<1, 64, 0, stream>>>(hist, tbin);
    k_collect<<<g1, 256, 0, stream>>>(c0, c1, c2, tbin, cnt, cand);
    k_sort<<<B_IMG, 1024, 0, stream>>>(cnt, cand, b0, b1, b2, tbox, tsc);
    k_mask<<<dim3(4, B_IMG), 256, 0, stream>>>(tbox, mask);
    k_nms_out<<<B_IMG, 64, 0, stream>>>(tbox, tsc, mask, (float*)d_out);
}

// Round 2
// 502.559 us; speedup vs baseline: 1.5534x; 1.5534x over previous
//
#include <hip/hip_runtime.h>
#include <stdint.h>

typedef unsigned int u32;
typedef unsigned long long u64;

#define B_IMG 16
#define NBINS 4096
#define CAP   2048
#define SORT_N 2048
#define TOPK  1000
#define NBLK  16          /* ceil(1000/64) */
#define SCORE_TH 0.05f

#define HW0 16384
#define HW1 4096
#define HW2 1024
#define L0  147456
#define L1  36864
#define L2  9216
#define NANCH 193536
#define O1  147456
#define O2  184320

__device__ __forceinline__ float score_of(float x) {
    return 1.0f / (1.0f + expf(-x));
}

__device__ __forceinline__ float load_logit(int b, int n,
        const float* __restrict__ c0, const float* __restrict__ c1,
        const float* __restrict__ c2) {
    if (n < O1)      return c0[b * L0 + n];
    else if (n < O2) return c1[b * L1 + (n - O1)];
    else             return c2[b * L2 + (n - O2)];
}

// exact same IoU arithmetic as round 1 (absmax was 0.0)
__device__ __forceinline__ bool iou_gt_half(float4 bi, float areai, float4 bj) {
    float xx1 = fmaxf(bi.x, bj.x), yy1 = fmaxf(bi.y, bj.y);
    float xx2 = fminf(bi.z, bj.z), yy2 = fminf(bi.w, bj.w);
    float iw = fmaxf(xx2 - xx1, 0.0f), ih = fmaxf(yy2 - yy1, 0.0f);
    float inter = iw * ih;
    float areaj = (bj.z - bj.x) * (bj.w - bj.y);
    float iou = inter / (areai + areaj - inter + 1e-8f);
    return iou > 0.5f;
}

// ---------------- kernel 1: per-image score histogram ----------------
__global__ void k_hist(const float* __restrict__ c0, const float* __restrict__ c1,
                       const float* __restrict__ c2, u32* __restrict__ hist) {
    __shared__ u32 lh[NBINS];
    for (int i = threadIdx.x; i < NBINS; i += blockDim.x) lh[i] = 0;
    __syncthreads();
    const int b  = blockIdx.y;
    const int n0 = blockIdx.x * 16384;
    for (int t = threadIdx.x; t < 16384; t += blockDim.x) {
        int n = n0 + t;
        if (n < NANCH) {
            float s = score_of(load_logit(b, n, c0, c1, c2));
            int bin = (int)(s * (float)NBINS);
            bin = min(max(bin, 0), NBINS - 1);
            atomicAdd(&lh[bin], 1u);
        }
    }
    __syncthreads();
    for (int i = threadIdx.x; i < NBINS; i += blockDim.x) {
        u32 v = lh[i];
        if (v) atomicAdd(&hist[b * NBINS + i], v);
    }
}

// ---------------- kernel 2: per-image threshold bin (parallel) ----------------
__global__ void k_thresh(const u32* __restrict__ hist, u32* __restrict__ tbin) {
    __shared__ u32 suf[256];
    const int b = blockIdx.x;
    const int t = threadIdx.x;  // 256 threads, 16 bins each
    u32 s = 0;
    #pragma unroll
    for (int i = 0; i < 16; ++i) s += hist[b * NBINS + t * 16 + i];
    suf[t] = s;
    __syncthreads();
    // inclusive suffix sum by doubling
    for (int d = 1; d < 256; d <<= 1) {
        u32 v = (t + d < 256) ? suf[t + d] : 0;
        __syncthreads();
        suf[t] += v;
        __syncthreads();
    }
    u32 mine = suf[t];
    u32 next = (t < 255) ? suf[t + 1] : 0;
    if (t == 0 && mine < TOPK) tbin[b] = 0;  // fallback: take everything
    if (mine >= TOPK && (t == 255 || next < TOPK)) {
        u32 cum = next;
        int T = t * 16;
        for (int bin = t * 16 + 15; bin >= t * 16; --bin) {
            cum += hist[b * NBINS + bin];
            if (cum >= TOPK) { T = bin; break; }
        }
        tbin[b] = (u32)T;
    }
}

// ---------------- kernel 3: collect candidates (wave-aggregated atomics) ----------------
__global__ void k_collect(const float* __restrict__ c0, const float* __restrict__ c1,
                          const float* __restrict__ c2, const u32* __restrict__ tbin,
                          u32* __restrict__ cnt, uint2* __restrict__ cand) {
    const int b  = blockIdx.y;
    const int T  = (int)tbin[b];
    const int n0 = blockIdx.x * 16384;
    const int lane = threadIdx.x & 63;
    for (int t = threadIdx.x; t < 16384; t += blockDim.x) {
        int n = n0 + t;
        bool take = false;
        float s = 0.0f;
        if (n < NANCH) {
            s = score_of(load_logit(b, n, c0, c1, c2));
            int bin = (int)(s * (float)NBINS);
            bin = min(max(bin, 0), NBINS - 1);
            take = (bin >= T);
        }
        u64 bal = __ballot(take);
        if (bal) {
            int leader = __ffsll((long long)bal) - 1;
            u32 base = 0;
            if (lane == leader) base = atomicAdd(&cnt[b], (u32)__popcll(bal));
            base = __shfl(base, leader);
            if (take) {
                u32 pos = base + (u32)__popcll(bal & ((1ull << lane) - 1ull));
                if (pos < CAP)
                    cand[b * CAP + pos] = make_uint2(__float_as_uint(s), (u32)n);
            }
        }
    }
}

// ---------------- box decode for one anchor (unchanged arithmetic) ----------------
__device__ __forceinline__ float4 decode_one(u32 n, int b,
        const float* __restrict__ bx0, const float* __restrict__ bx1,
        const float* __restrict__ bx2) {
    int a, p, X, Y, stride, HW;
    float base;
    const float* bptr;
    if (n < O1) {
        a = n >> 14; p = n & (HW0 - 1); X = p & 127; Y = p >> 7;
        stride = 8; base = 32.0f; HW = HW0;
        bptr = bx0 + ((b * 9 + a) * 4) * HW0 + p;
    } else if (n < O2) {
        u32 wi = n - O1;
        a = wi >> 12; p = wi & (HW1 - 1); X = p & 63; Y = p >> 6;
        stride = 16; base = 64.0f; HW = HW1;
        bptr = bx1 + ((b * 9 + a) * 4) * HW1 + p;
    } else {
        u32 wi = n - O2;
        a = wi >> 10; p = wi & (HW2 - 1); X = p & 31; Y = p >> 5;
        stride = 32; base = 128.0f; HW = HW2;
        bptr = bx2 + ((b * 9 + a) * 4) * HW2 + p;
    }
    float tx = bptr[0], ty = bptr[HW], tw = bptr[2 * HW], th = bptr[3 * HW];
    int sci = a / 3, ri = a % 3;
    const float SCALE3[3] = {1.0f, 1.2599210498948732f, 1.5874010519681994f};
    const float SQRTR[3]  = {0.7071067811865476f, 1.0f, 1.4142135623730951f};
    float size = base * SCALE3[sci];
    float aw = size * SQRTR[ri];
    float ah = size / SQRTR[ri];
    float cx = ((float)X + 0.5f) * (float)stride;
    float cy = ((float)Y + 0.5f) * (float)stride;
    float gx = tx * aw + cx;
    float gy = ty * ah + cy;
    float gw = aw * expf(tw);
    float gh = ah * expf(th);
    return make_float4(gx - 0.5f * gw, gy - 0.5f * gh, gx + 0.5f * gw, gy + 0.5f * gh);
}

// ---------------- kernel 4: fused sort + decode + blocked-greedy-NMS + output ----------------
__global__ __launch_bounds__(1024) void k_fused(const u32* __restrict__ cnt,
        const uint2* __restrict__ cand,
        const float* __restrict__ bx0, const float* __restrict__ bx1,
        const float* __restrict__ bx2,
        float* __restrict__ out) {
    __shared__ u64 keys[SORT_N];          // 16 KB
    __shared__ float4 bl[TOPK];           // 16 KB
    __shared__ float sc[TOPK];            // 4 KB
    __shared__ u64 Mintra[NBLK][64];      // 8 KB: intra-block suppression rows
    __shared__ u64 Snew[NBLK];
    __shared__ u64 keepbits[NBLK];
    __shared__ u64 keepw_sh;

    const int b = blockIdx.x;
    const int tid = threadIdx.x;
    const int m = (int)min(cnt[b], (u32)CAP);

    // ---- load candidate keys (score<<32 | ~idx → desc score, asc idx) ----
    for (int i = tid; i < SORT_N; i += 1024) {
        u64 k = 0;
        if (i < m) {
            uint2 c = cand[b * CAP + i];
            k = ((u64)c.x << 32) | (u64)((u32)(~c.y));
        }
        keys[i] = k;
    }
    __syncthreads();

    // ---- bitonic sort, descending, 1024 threads / 2048 keys ----
    for (int k = 2; k <= SORT_N; k <<= 1) {
        for (int j = k >> 1; j > 0; j >>= 1) {
            int idx = ((tid & ~(j - 1)) << 1) | (tid & (j - 1));
            int ixj = idx | j;
            bool up = ((idx & k) == 0);
            u64 a = keys[idx], c2 = keys[ixj];
            if (up ? (a < c2) : (a > c2)) { keys[idx] = c2; keys[ixj] = a; }
            __syncthreads();
        }
    }

    // ---- decode top-1000 into LDS ----
    if (tid < TOPK) {
        float s = 0.0f;
        float4 box = make_float4(0.f, 0.f, 0.f, 0.f);
        if (tid < m) {
            u64 kk = keys[tid];
            s = __uint_as_float((u32)(kk >> 32));
            u32 n = ~((u32)kk);
            box = decode_one(n, b, bx0, bx1, bx2);
        }
        sc[tid] = s;
        bl[tid] = box;
    }
    __syncthreads();

    // ---- intra-block suppression words: row i, bits j in same 64-block, j>i ----
    {
        int lane = tid & 63;
        for (int r = tid >> 6; r < NBLK * 64; r += 16) {
            int i = r;
            int j = (r & ~63) | lane;
            bool pred = false;
            if (i < TOPK && j < TOPK && j > i) {
                float4 bi = bl[i];
                float areai = (bi.z - bi.x) * (bi.w - bi.y);
                pred = iou_gt_half(bi, areai, bl[j]);
            }
            u64 bal = __ballot(pred);
            if (lane == 0) Mintra[i >> 6][i & 63] = bal;
        }
    }
    __syncthreads();

    // per-thread box registers for the future-suppression phase
    float4 bj4 = make_float4(0.f, 0.f, 0.f, 0.f);
    float sj = 0.0f;
    if (tid < TOPK) { bj4 = bl[tid]; sj = sc[tid]; }
    bool supj_total = false;

    u64 Sfut = 0;  // wave0 lane u (u<16): accumulated suppression word for block u

    for (int t = 0; t < NBLK; ++t) {
        // -- wave 0: serial scan of block t (register/shfl only) --
        if (tid < 64) {
            int lane = tid;
            u64 supw = __shfl(Sfut, t);          // uniform across lanes
            u64 Mk = Mintra[t][lane];
            int gi = 64 * t + lane;
            float sck = (gi < TOPK) ? sc[gi] : 0.0f;
            u64 kw = 0;
            #pragma unroll 4
            for (int k2 = 0; k2 < 64; ++k2) {
                if (!((supw >> k2) & 1ull)) {            // uniform branch
                    float s_k = __shfl(sck, k2);
                    if (s_k > SCORE_TH) {                // uniform branch
                        supw |= __shfl(Mk, k2);
                        kw |= (1ull << k2);
                    }
                }
            }
            if (lane == 0) { keepbits[t] = kw; keepw_sh = kw; }
        }
        __syncthreads();

        // -- all threads: suppression of future j by kept rows of block t --
        u64 kw = keepw_sh;
        bool pred = false;
        if (tid < TOPK && (tid >> 6) > t && !supj_total && sj > SCORE_TH && kw) {
            u64 w2 = kw;
            while (w2) {
                int k2 = __ffsll((long long)w2) - 1;
                w2 &= w2 - 1;
                float4 bi = bl[64 * t + k2];   // LDS broadcast
                float areai = (bi.z - bi.x) * (bi.w - bi.y);
                if (iou_gt_half(bi, areai, bj4)) { pred = true; break; }
            }
        }
        supj_total = supj_total || pred;
        u64 bal = __ballot(pred);
        if ((tid & 63) == 0) Snew[tid >> 6] = bal;
        __syncthreads();
        if (tid < NBLK) Sfut |= Snew[tid];   // wave 0 only; consumed by same wave next iter
    }

    // ---- output (keepbits final after last barrier) ----
    for (int j2 = tid; j2 < TOPK; j2 += 1024) {
        float kf = ((keepbits[j2 >> 6] >> (j2 & 63)) & 1ull) ? 1.0f : 0.0f;
        float4 bx = bl[j2];
        float s = sc[j2];
        float* o = out + ((size_t)b * TOPK + j2) * 5;
        o[0] = bx.x * kf;
        o[1] = bx.y * kf;
        o[2] = bx.z * kf;
        o[3] = bx.w * kf;
        o[4] = s * kf;
    }
}

extern "C" void kernel_launch(void* const* d_in, const int* in_sizes, int n_in,
                              void* d_out, int out_size, void* d_ws, size_t ws_size,
                              hipStream_t stream) {
    const float* c0 = (const float*)d_in[0];
    const float* c1 = (const float*)d_in[1];
    const float* c2 = (const float*)d_in[2];
    const float* b0 = (const float*)d_in[3];
    const float* b1 = (const float*)d_in[4];
    const float* b2 = (const float*)d_in[5];

    char* ws = (char*)d_ws;
    size_t off = 0;
    u32*   hist = (u32*)(ws + off);   off += (size_t)B_IMG * NBINS * 4;   // 256 KiB
    u32*   tbin = (u32*)(ws + off);   off += 256;
    u32*   cnt  = (u32*)(ws + off);   off += 256;
    uint2* cand = (uint2*)(ws + off); off += (size_t)B_IMG * CAP * 8;     // 256 KiB

    // zero hist + tbin + cnt every call
    hipMemsetAsync(d_ws, 0, (size_t)B_IMG * NBINS * 4 + 512, stream);

    dim3 g1(12, B_IMG);
    k_hist<<<g1, 256, 0, stream>>>(c0, c1, c2, hist);
    k_thresh<<<B_IMG, 256, 0, stream>>>(hist, tbin);
    k_collect<<<g1, 256, 0, stream>>>(c0, c1, c2, tbin, cnt, cand);
    k_fused<<<B_IMG, 1024, 0, stream>>>(cnt, cand, b0, b1, b2, (float*)d_out);
}